// Round 2
// baseline (329.929 us; speedup 1.0000x reference)
//
#include <hip/hip_runtime.h>
#include <math.h>

#define B_    2048
#define M_    200
#define DQ_   512
#define DT_   768
#define DA_   64
#define G_    4              // batches per block
#define NEG_INF_ (-1e30f)

typedef float f4 __attribute__((ext_vector_type(4)));

__device__ __forceinline__ float dot4f(f4 a, f4 b) {
    return a[0]*b[0] + a[1]*b[1] + a[2]*b[2] + a[3]*b[3];
}
__device__ __forceinline__ void fma4(f4& a, float e, f4 c) {
    a[0] += e*c[0]; a[1] += e*c[1]; a[2] += e*c[2]; a[3] += e*c[3];
}
__device__ __forceinline__ void scale_add4(f4& a, float sc, f4 c) {
    a[0] = a[0]*sc + c[0]; a[1] = a[1]*sc + c[1];
    a[2] = a[2]*sc + c[2]; a[3] = a[3]*sc + c[3];
}
__device__ __forceinline__ f4 ntld4(const float* p) {
    return __builtin_nontemporal_load((const f4*)p);
}
__device__ __forceinline__ void ntst(float* p, float v) {
    __builtin_nontemporal_store(v, p);
}

// One block = G_ (4) batch elements, 512 threads = 8 waves, 2 waves per batch.
// Every weight element is read ONCE per block and reused for 4 batches via
// register FMA — cuts weight cache traffic 4x (1.34 GB -> 335 MB).
// desc is streamed with non-temporal loads (zero reuse; keep L2 for weights).
__global__ __launch_bounds__(512, 4)
void bilinear_attn_fused(const float* __restrict__ q_vec,
                         const float* __restrict__ desc,
                         const int*   __restrict__ mask,
                         const float* __restrict__ Wq,
                         const float* __restrict__ Wk,
                         const float* __restrict__ Wv,
                         const float* __restrict__ U,
                         const float* __restrict__ Wo,
                         const float* __restrict__ bo,
                         float* __restrict__ out_fused,
                         float* __restrict__ out_attn)
{
    const int tid  = threadIdx.x;
    const int lane = tid & 63;
    const int wv_  = tid >> 6;            // wave 0..7
    const int b0   = blockIdx.x * G_;

    __shared__ float s_qv[G_][DQ_];       // 8 KB   staged q rows
    __shared__ float s_Q[G_][DA_];        // 1 KB
    __shared__ float s_QU[G_][DA_];       // 1 KB
    __shared__ float s_w[G_][DT_];        // 12 KB  w vectors, then sbar
    __shared__ float s_wacc[8][DT_];      // 24 KB  per-wave acc, then ctx partials
    __shared__ float s_scores[G_][M_];    // 3.2 KB
    __shared__ int   s_msk[G_][M_];       // 3.2 KB
    __shared__ float s_red[512];          // 2 KB
    __shared__ float s_wm[8], s_wl[8];
    __shared__ float s_ctx[G_][DA_];      // 1 KB

    // ---- stage q rows + masks ----
    for (int i = tid; i < G_ * DQ_; i += 512) {
        const int gg = i >> 9, j = i & (DQ_ - 1);
        s_qv[gg][j] = q_vec[(size_t)(b0 + gg) * DQ_ + j];
    }
    #pragma unroll
    for (int gg = 0; gg < G_; ++gg)
        for (int m = tid; m < M_; m += 512)
            s_msk[gg][m] = mask[(size_t)(b0 + gg) * M_ + m];
    __syncthreads();

    // ---- Q_g = qv_g @ Wq  (each Wq element read once, 4-way ... split t 2-way) ----
    {
        const int h = tid >> 8;           // t-half
        const int r = tid & 255;
        const int gg = r >> 6, d = r & 63;
        float p = 0.f;
        const int t0 = h * (DQ_ / 2);
        for (int t = t0; t < t0 + DQ_ / 2; ++t)
            p += s_qv[gg][t] * Wq[t * DA_ + d];
        s_red[tid] = p;
    }
    __syncthreads();
    if (tid < 256) {
        const int gg = tid >> 6, d = tid & 63;
        s_Q[gg][d] = s_red[tid] + s_red[tid + 256];
    }
    __syncthreads();

    // ---- QU_g = Q_g @ U ----
    if (tid < 256) {
        const int gg = tid >> 6, d = tid & 63;
        float qu = 0.f;
        for (int e = 0; e < DA_; ++e) qu += s_Q[gg][e] * U[e * DA_ + d];
        s_QU[gg][d] = qu;
    }
    __syncthreads();

    // ---- w_g[t] = Wk[t,:] . QU_g   (each Wk element read once, 4 FMA reuse) ----
    for (int t = tid; t < DT_; t += 512) {
        const f4* wk4 = (const f4*)(Wk + (size_t)t * DA_);
        float a0 = 0.f, a1 = 0.f, a2 = 0.f, a3 = 0.f;
        #pragma unroll
        for (int i = 0; i < DA_ / 4; ++i) {
            const f4 kk = wk4[i];
            a0 += dot4f(kk, *(const f4*)&s_QU[0][i * 4]);
            a1 += dot4f(kk, *(const f4*)&s_QU[1][i * 4]);
            a2 += dot4f(kk, *(const f4*)&s_QU[2][i * 4]);
            a3 += dot4f(kk, *(const f4*)&s_QU[3][i * 4]);
        }
        s_w[0][t] = a0; s_w[1][t] = a1; s_w[2][t] = a2; s_w[3][t] = a3;
    }
    __syncthreads();

    // ---- stream: wave wv_ handles batch g = wv_>>1, rows sub, sub+2, ... ----
    const int g   = wv_ >> 1;
    const int sub = wv_ & 1;
    const int off0 = lane * 4, off1 = lane * 4 + 256, off2 = lane * 4 + 512;
    const f4 w0 = *(const f4*)&s_w[g][off0];
    const f4 w1 = *(const f4*)&s_w[g][off1];
    const f4 w2 = *(const f4*)&s_w[g][off2];

    const float* descb = desc + (size_t)(b0 + g) * M_ * DT_;

    f4 acc0 = {0,0,0,0}, acc1 = {0,0,0,0}, acc2 = {0,0,0,0};
    float mw = -INFINITY, lw = 0.f;

    f4 c0, c1, c2;
    {
        const float* r = descb + (size_t)sub * DT_;
        c0 = ntld4(r + off0); c1 = ntld4(r + off1); c2 = ntld4(r + off2);
    }
    for (int row = sub; row < M_; row += 2) {
        f4 n0 = {0,0,0,0}, n1 = {0,0,0,0}, n2 = {0,0,0,0};
        const int nrow = row + 2;
        if (nrow < M_) {
            const float* r = descb + (size_t)nrow * DT_;
            n0 = ntld4(r + off0); n1 = ntld4(r + off1); n2 = ntld4(r + off2);
        }
        float p = dot4f(c0, w0) + dot4f(c1, w1) + dot4f(c2, w2);
        #pragma unroll
        for (int o = 32; o >= 1; o >>= 1) p += __shfl_xor(p, o, 64);
        const float s = (s_msk[g][row] == 0) ? NEG_INF_ : p;
        if (lane == 0) s_scores[g][row] = s;

        if (s <= mw) {                       // wave-uniform branch
            const float e = __expf(s - mw);
            lw += e;
            fma4(acc0, e, c0); fma4(acc1, e, c1); fma4(acc2, e, c2);
        } else {
            const float sc = __expf(mw - s);
            lw = lw * sc + 1.f;
            scale_add4(acc0, sc, c0); scale_add4(acc1, sc, c1); scale_add4(acc2, sc, c2);
            mw = s;
        }
        c0 = n0; c1 = n1; c2 = n2;
    }
    if (lane == 0) { s_wm[wv_] = mw; s_wl[wv_] = lw; }
    *(f4*)&s_wacc[wv_][off0] = acc0;
    *(f4*)&s_wacc[wv_][off1] = acc1;
    *(f4*)&s_wacc[wv_][off2] = acc2;
    __syncthreads();

    // ---- merge the 2 wave-states per batch; normalize; emit attn ----
    float Mx[G_], il[G_], fa[G_], fb[G_];
    #pragma unroll
    for (int gg = 0; gg < G_; ++gg) {
        const float ma = s_wm[2 * gg], mb = s_wm[2 * gg + 1];
        const float mx = fmaxf(ma, mb);
        const float f0 = __expf(ma - mx), f1 = __expf(mb - mx);
        const float lt = s_wl[2 * gg] * f0 + s_wl[2 * gg + 1] * f1;
        Mx[gg] = mx; fa[gg] = f0; fb[gg] = f1; il[gg] = 1.0f / lt;
    }
    for (int t = tid; t < DT_; t += 512) {
        #pragma unroll
        for (int gg = 0; gg < G_; ++gg)
            s_w[gg][t] = (s_wacc[2*gg][t] * fa[gg] + s_wacc[2*gg+1][t] * fb[gg]) * il[gg];
    }
    #pragma unroll
    for (int gg = 0; gg < G_; ++gg)
        for (int m = tid; m < M_; m += 512)
            ntst(out_attn + (size_t)(b0 + gg) * M_ + m,
                 __expf(s_scores[gg][m] - Mx[gg]) * il[gg]);
    __syncthreads();

    // ---- ctx_g = sbar_g @ Wv   (each Wv element read once, 4 FMA reuse) ----
    {
        const int t0 = wv_ * (DT_ / 8);        // 96 t's per wave
        float p0 = 0.f, p1 = 0.f, p2 = 0.f, p3 = 0.f;
        for (int k = 0; k < DT_ / 8; ++k) {
            const int t = t0 + k;
            const float wvv = Wv[(size_t)t * DA_ + lane];
            p0 += s_w[0][t] * wvv; p1 += s_w[1][t] * wvv;
            p2 += s_w[2][t] * wvv; p3 += s_w[3][t] * wvv;
        }
        s_wacc[wv_][0 * DA_ + lane] = p0;
        s_wacc[wv_][1 * DA_ + lane] = p1;
        s_wacc[wv_][2 * DA_ + lane] = p2;
        s_wacc[wv_][3 * DA_ + lane] = p3;
    }
    __syncthreads();
    if (tid < 256) {
        const int gg = tid >> 6, d = tid & 63;
        float c = 0.f;
        #pragma unroll
        for (int w = 0; w < 8; ++w) c += s_wacc[w][gg * DA_ + d];
        s_ctx[gg][d] = c;
    }
    __syncthreads();

    // ---- fused_g = ctx_g @ Wo + bo + qv_g   (each Wo element read once) ----
    {
        const int j = tid;                    // DQ_ == 512 == blockDim
        float f0 = bo[j] + s_qv[0][j];
        float f1 = bo[j] + s_qv[1][j];
        float f2 = bo[j] + s_qv[2][j];
        float f3 = bo[j] + s_qv[3][j];
        for (int d = 0; d < DA_; ++d) {
            const float wo = Wo[(size_t)d * DQ_ + j];
            f0 += s_ctx[0][d] * wo; f1 += s_ctx[1][d] * wo;
            f2 += s_ctx[2][d] * wo; f3 += s_ctx[3][d] * wo;
        }
        ntst(out_fused + (size_t)(b0 + 0) * DQ_ + j, f0);
        ntst(out_fused + (size_t)(b0 + 1) * DQ_ + j, f1);
        ntst(out_fused + (size_t)(b0 + 2) * DQ_ + j, f2);
        ntst(out_fused + (size_t)(b0 + 3) * DQ_ + j, f3);
    }
}

extern "C" void kernel_launch(void* const* d_in, const int* in_sizes, int n_in,
                              void* d_out, int out_size, void* d_ws, size_t ws_size,
                              hipStream_t stream) {
    (void)in_sizes; (void)n_in; (void)d_ws; (void)ws_size; (void)out_size;

    const float* q_vec = (const float*)d_in[0];
    const float* desc  = (const float*)d_in[1];
    const int*   mask  = (const int*)  d_in[2];
    const float* Wq    = (const float*)d_in[3];
    const float* Wk    = (const float*)d_in[4];
    const float* Wv    = (const float*)d_in[5];
    const float* U     = (const float*)d_in[6];
    const float* Wo    = (const float*)d_in[7];
    const float* bo    = (const float*)d_in[8];

    float* out_fused = (float*)d_out;                     // (B, DQ)
    float* out_attn  = (float*)d_out + (size_t)B_ * DQ_;  // (B, M)

    bilinear_attn_fused<<<dim3(B_ / G_), dim3(512), 0, stream>>>(
        q_vec, desc, mask, Wq, Wk, Wv, U, Wo, bo, out_fused, out_attn);
}

// Round 3
// 196.061 us; speedup vs baseline: 1.6828x; 1.6828x over previous
//
#include <hip/hip_runtime.h>
#include <math.h>

#define B_    2048
#define M_    200
#define DQ_   512
#define DT_   768
#define DA_   64
#define NEG_INF_ (-1e30f)

typedef float f4 __attribute__((ext_vector_type(4)));

__device__ __forceinline__ float dot4f(f4 a, f4 b) {
    return a[0]*b[0] + a[1]*b[1] + a[2]*b[2] + a[3]*b[3];
}
__device__ __forceinline__ void fma4(f4& a, float e, f4 c) {
    a[0] += e*c[0]; a[1] += e*c[1]; a[2] += e*c[2]; a[3] += e*c[3];
}
__device__ __forceinline__ void scale_add4(f4& a, float sc, f4 c) {
    a[0] = a[0]*sc + c[0]; a[1] = a[1]*sc + c[1];
    a[2] = a[2]*sc + c[2]; a[3] = a[3]*sc + c[3];
}

// One block per batch element (R1 structure), PLUS masked-row skipping:
// ~50% of desc rows are masked and contribute exactly 0 (exp(-1e30 - Mx)
// underflows). Wave 0 ballot-compacts the unmasked row indices
// (deterministic order); the 4 waves stream only those rows.
// desc traffic: 1.26 GB -> ~0.63 GB.
__global__ __launch_bounds__(256, 4)
void bilinear_attn_fused(const float* __restrict__ q_vec,
                         const float* __restrict__ desc,
                         const int*   __restrict__ mask,
                         const float* __restrict__ Wq,
                         const float* __restrict__ Wk,
                         const float* __restrict__ Wv,
                         const float* __restrict__ U,
                         const float* __restrict__ Wo,
                         const float* __restrict__ bo,
                         float* __restrict__ out_fused,
                         float* __restrict__ out_attn)
{
    const int b    = blockIdx.x;
    const int tid  = threadIdx.x;
    const int lane = tid & 63;
    const int wv_  = tid >> 6;

    __shared__ float s_qv[DQ_];
    __shared__ float s_red[256];
    __shared__ float s_Q[DA_];
    __shared__ float s_QU[DA_];
    __shared__ float s_w[DT_];
    __shared__ int   s_idx[M_];        // compacted unmasked row indices
    __shared__ float s_sc[M_];         // full-size scores, init NEG_INF
    __shared__ int   s_cnt;
    __shared__ float s_wm[4], s_wl[4];
    __shared__ float s_acc[4][DT_];
    __shared__ float s_ctx[DA_];

    const float* qrow  = q_vec + (size_t)b * DQ_;
    const int*   maskb = mask  + (size_t)b * M_;

    // ---- wave 0: ballot-compact unmasked rows; waves 1-3: stage q row ----
    if (wv_ == 0) {
        int total = 0;
        #pragma unroll
        for (int base = 0; base < 256; base += 64) {
            const int m  = base + lane;
            const int mk = (m < M_) ? maskb[m] : 0;
            const unsigned long long bal = __ballot(mk != 0);
            const int pre = __popcll(bal & ((1ull << lane) - 1ull));
            if (mk) s_idx[total + pre] = m;
            total += __popcll(bal);
        }
        if (lane == 0) s_cnt = total;
    } else {
        for (int i = tid - 64; i < DQ_; i += 192) s_qv[i] = qrow[i];
    }
    for (int m = tid; m < M_; m += 256) s_sc[m] = NEG_INF_;
    __syncthreads();

    // ---- Q = qv @ Wq ----
    {
        const int d  = lane;
        const int t0 = wv_ * (DQ_ / 4);
        float p = 0.f;
        for (int t = t0; t < t0 + DQ_ / 4; ++t)
            p += s_qv[t] * Wq[t * DA_ + d];
        s_red[tid] = p;
    }
    __syncthreads();
    if (tid < DA_)
        s_Q[tid] = s_red[tid] + s_red[tid + 64] + s_red[tid + 128] + s_red[tid + 192];
    __syncthreads();

    // ---- QU = Q @ U ----
    if (tid < DA_) {
        float qu = 0.f;
        for (int e = 0; e < DA_; ++e) qu += s_Q[e] * U[e * DA_ + tid];
        s_QU[tid] = qu;
    }
    __syncthreads();

    // ---- w[t] = Wk[t,:] . QU ----
    for (int t = tid; t < DT_; t += 256) {
        const f4* wk4 = (const f4*)(Wk + (size_t)t * DA_);
        const f4* qu4 = (const f4*)s_QU;
        float a = 0.f;
        #pragma unroll
        for (int i = 0; i < DA_ / 4; ++i) a += dot4f(wk4[i], qu4[i]);
        s_w[t] = a;
    }
    __syncthreads();

    const int off0 = lane * 4, off1 = lane * 4 + 256, off2 = lane * 4 + 512;
    const f4 w0 = *(const f4*)&s_w[off0];
    const f4 w1 = *(const f4*)&s_w[off1];
    const f4 w2 = *(const f4*)&s_w[off2];

    // ---- stream only unmasked rows (compact list), online softmax ----
    const float* descb = desc + (size_t)b * M_ * DT_;
    const int    Nu    = s_cnt;

    f4 acc0 = {0,0,0,0}, acc1 = {0,0,0,0}, acc2 = {0,0,0,0};
    float mw = -INFINITY, lw = 0.f;

    f4 c0 = {0,0,0,0}, c1 = {0,0,0,0}, c2 = {0,0,0,0};
    if (wv_ < Nu) {
        const float* r = descb + (size_t)s_idx[wv_] * DT_;
        c0 = *(const f4*)(r + off0);
        c1 = *(const f4*)(r + off1);
        c2 = *(const f4*)(r + off2);
    }
    for (int j = wv_; j < Nu; j += 4) {
        const int row = s_idx[j];
        f4 n0 = {0,0,0,0}, n1 = {0,0,0,0}, n2 = {0,0,0,0};
        const int nj = j + 4;
        if (nj < Nu) {
            const float* r = descb + (size_t)s_idx[nj] * DT_;
            n0 = *(const f4*)(r + off0);
            n1 = *(const f4*)(r + off1);
            n2 = *(const f4*)(r + off2);
        }
        float p = dot4f(c0, w0) + dot4f(c1, w1) + dot4f(c2, w2);
        #pragma unroll
        for (int o = 32; o >= 1; o >>= 1) p += __shfl_xor(p, o, 64);
        if (lane == 0) s_sc[row] = p;

        // online softmax update (p is wave-uniform)
        if (p <= mw) {
            const float e = __expf(p - mw);
            lw += e;
            fma4(acc0, e, c0); fma4(acc1, e, c1); fma4(acc2, e, c2);
        } else {
            const float sc = __expf(mw - p);
            lw = lw * sc + 1.f;
            scale_add4(acc0, sc, c0); scale_add4(acc1, sc, c1); scale_add4(acc2, sc, c2);
            mw = p;
        }
        c0 = n0; c1 = n1; c2 = n2;
    }

    if (lane == 0) { s_wm[wv_] = mw; s_wl[wv_] = lw; }
    *(f4*)&s_acc[wv_][off0] = acc0;
    *(f4*)&s_acc[wv_][off1] = acc1;
    *(f4*)&s_acc[wv_][off2] = acc2;
    __syncthreads();

    // ---- merge 4 wave states ----
    const float m0 = s_wm[0], m1 = s_wm[1], m2 = s_wm[2], m3 = s_wm[3];
    const float Mx = fmaxf(fmaxf(fmaxf(m0, m1), fmaxf(m2, m3)), -3.0e29f);
    const float f0 = __expf(m0 - Mx), f1 = __expf(m1 - Mx);
    const float f2 = __expf(m2 - Mx), f3 = __expf(m3 - Mx);
    const float ltot  = s_wl[0]*f0 + s_wl[1]*f1 + s_wl[2]*f2 + s_wl[3]*f3;
    const float inv_l = (ltot > 0.f) ? (1.0f / ltot) : 0.f;

    for (int t = tid; t < DT_; t += 256) {
        const float v = s_acc[0][t]*f0 + s_acc[1][t]*f1
                      + s_acc[2][t]*f2 + s_acc[3][t]*f3;
        s_acc[0][t] = v * inv_l;
    }
    // attn: masked rows have s_sc == -1e30 -> exp underflows to exact 0
    for (int m = tid; m < M_; m += 256)
        out_attn[(size_t)b * M_ + m] = __expf(s_sc[m] - Mx) * inv_l;
    __syncthreads();

    // ---- ctx[d] = sbar . Wv[:,d] ----
    {
        const int d  = lane;
        const int t0 = wv_ * (DT_ / 4);
        float cp = 0.f;
        for (int t = t0; t < t0 + DT_ / 4; ++t)
            cp += s_acc[0][t] * Wv[(size_t)t * DA_ + d];
        s_red[tid] = cp;
    }
    __syncthreads();
    if (tid < DA_)
        s_ctx[tid] = s_red[tid] + s_red[tid + 64] + s_red[tid + 128] + s_red[tid + 192];
    __syncthreads();

    // ---- fused = ctx @ Wo + bo + q_vec ----
    for (int j = tid; j < DQ_; j += 256) {
        float f = bo[j] + s_qv[j];
        #pragma unroll 8
        for (int d = 0; d < DA_; ++d)
            f += s_ctx[d] * Wo[(size_t)d * DQ_ + j];
        out_fused[(size_t)b * DQ_ + j] = f;
    }
}

extern "C" void kernel_launch(void* const* d_in, const int* in_sizes, int n_in,
                              void* d_out, int out_size, void* d_ws, size_t ws_size,
                              hipStream_t stream) {
    (void)in_sizes; (void)n_in; (void)d_ws; (void)ws_size; (void)out_size;

    const float* q_vec = (const float*)d_in[0];
    const float* desc  = (const float*)d_in[1];
    const int*   mask  = (const int*)  d_in[2];
    const float* Wq    = (const float*)d_in[3];
    const float* Wk    = (const float*)d_in[4];
    const float* Wv    = (const float*)d_in[5];
    const float* U     = (const float*)d_in[6];
    const float* Wo    = (const float*)d_in[7];
    const float* bo    = (const float*)d_in[8];

    float* out_fused = (float*)d_out;                     // (B, DQ)
    float* out_attn  = (float*)d_out + (size_t)B_ * DQ_;  // (B, M)

    bilinear_attn_fused<<<dim3(B_), dim3(256), 0, stream>>>(
        q_vec, desc, mask, Wq, Wk, Wv, U, Wo, bo, out_fused, out_attn);
}

// Round 4
// 194.127 us; speedup vs baseline: 1.6996x; 1.0100x over previous
//
#include <hip/hip_runtime.h>
#include <math.h>

#define B_    2048
#define M_    200
#define DQ_   512
#define DT_   768
#define DA_   64
#define NEG_INF_ (-1e30f)
#define MINIT_  (-3.0e29f)

typedef float f4 __attribute__((ext_vector_type(4)));

__device__ __forceinline__ float dot4f(f4 a, f4 b) {
    return a[0]*b[0] + a[1]*b[1] + a[2]*b[2] + a[3]*b[3];
}

// One block per batch element. Masked rows are skipped via ballot-compacted
// index list (they contribute exactly 0). Streaming uses HALF-WAVE row split:
// lanes 0-31 process row 2p, lanes 32-63 row 2p+1 (6 x f4 per lane), so the
// cross-lane reduce is 5 steps amortized over 2 rows, and in-flight bytes per
// wave double. Online softmax is branchless per half-wave (8 states merged).
__global__ __launch_bounds__(256, 4)
void bilinear_attn_fused(const float* __restrict__ q_vec,
                         const float* __restrict__ desc,
                         const int*   __restrict__ mask,
                         const float* __restrict__ Wq,
                         const float* __restrict__ Wk,
                         const float* __restrict__ Wv,
                         const float* __restrict__ U,
                         const float* __restrict__ Wo,
                         const float* __restrict__ bo,
                         float* __restrict__ out_fused,
                         float* __restrict__ out_attn)
{
    const int b    = blockIdx.x;
    const int tid  = threadIdx.x;
    const int lane = tid & 63;
    const int wv_  = tid >> 6;
    const int half = lane >> 5;
    const int hl   = lane & 31;

    __shared__ float s_qv[DQ_];
    __shared__ float s_red[256];
    __shared__ float s_Q[DA_];
    __shared__ float s_QU[DA_];
    __shared__ float s_w[DT_];
    __shared__ int   s_idx[M_];        // compacted unmasked row indices
    __shared__ float s_sc[M_];         // scores, init NEG_INF
    __shared__ int   s_cnt;
    __shared__ float s_wm[8], s_wl[8];
    __shared__ float s_acc[8][DT_];    // 24 KB: per-half-wave accumulators
    __shared__ float s_ctx[DA_];

    const float* qrow  = q_vec + (size_t)b * DQ_;
    const int*   maskb = mask  + (size_t)b * M_;

    // ---- wave 0: ballot-compact unmasked rows; waves 1-3: stage q ----
    if (wv_ == 0) {
        int total = 0;
        #pragma unroll
        for (int base = 0; base < 256; base += 64) {
            const int m  = base + lane;
            const int mk = (m < M_) ? maskb[m] : 0;
            const unsigned long long bal = __ballot(mk != 0);
            const int pre = __popcll(bal & ((1ull << lane) - 1ull));
            if (mk) s_idx[total + pre] = m;
            total += __popcll(bal);
        }
        if (lane == 0) s_cnt = total;
    } else {
        for (int i = tid - 64; i < DQ_; i += 192) s_qv[i] = qrow[i];
    }
    for (int m = tid; m < M_; m += 256) s_sc[m] = NEG_INF_;
    __syncthreads();

    // ---- Q = qv @ Wq ----
    {
        const int d  = lane;
        const int t0 = wv_ * (DQ_ / 4);
        float p = 0.f;
        for (int t = t0; t < t0 + DQ_ / 4; ++t)
            p += s_qv[t] * Wq[t * DA_ + d];
        s_red[tid] = p;
    }
    __syncthreads();
    if (tid < DA_)
        s_Q[tid] = s_red[tid] + s_red[tid + 64] + s_red[tid + 128] + s_red[tid + 192];
    __syncthreads();

    // ---- QU = Q @ U ----
    if (tid < DA_) {
        float qu = 0.f;
        for (int e = 0; e < DA_; ++e) qu += s_Q[e] * U[e * DA_ + tid];
        s_QU[tid] = qu;
    }
    __syncthreads();

    // ---- w[t] = Wk[t,:] . QU ----
    for (int t = tid; t < DT_; t += 256) {
        const f4* wk4 = (const f4*)(Wk + (size_t)t * DA_);
        const f4* qu4 = (const f4*)s_QU;
        float a = 0.f;
        #pragma unroll
        for (int i = 0; i < DA_ / 4; ++i) a += dot4f(wk4[i], qu4[i]);
        s_w[t] = a;
    }
    __syncthreads();

    // per-lane w slice: floats hl*4 + j*128, j=0..5 (identical for both halves)
    f4 wr[6];
    #pragma unroll
    for (int j = 0; j < 6; ++j)
        wr[j] = *(const f4*)&s_w[hl * 4 + j * 128];

    const float* descb = desc + (size_t)b * M_ * DT_;
    const int    Nu    = s_cnt;
    const int    npairs = (Nu + 1) >> 1;

    f4 acc[6] = {{0,0,0,0},{0,0,0,0},{0,0,0,0},{0,0,0,0},{0,0,0,0},{0,0,0,0}};
    float mw = MINIT_, lw = 0.f;

    if (Nu > 0) {
        const int last = Nu - 1;
        int rid;                       // current row id for this half-wave
        f4  c[6];
        {
            const int rp = 2 * wv_ + half;
            rid = s_idx[rp < last ? rp : last];
            const float* r = descb + (size_t)rid * DT_ + hl * 4;
            #pragma unroll
            for (int j = 0; j < 6; ++j) c[j] = *(const f4*)(r + j * 128);
        }
        for (int pp = wv_; pp < npairs; pp += 4) {
            const bool havenext = (pp + 4) < npairs;   // wave-uniform
            int nrid = 0;
            f4  n[6];
            if (havenext) {
                const int nrp = 2 * (pp + 4) + half;
                nrid = s_idx[nrp < last ? nrp : last];
                const float* r = descb + (size_t)nrid * DT_ + hl * 4;
                #pragma unroll
                for (int j = 0; j < 6; ++j) n[j] = *(const f4*)(r + j * 128);
            }

            // dot for this half's row, 5-step 32-lane reduce (2 rows at once)
            float p = dot4f(c[0], wr[0]) + dot4f(c[1], wr[1]) + dot4f(c[2], wr[2])
                    + dot4f(c[3], wr[3]) + dot4f(c[4], wr[4]) + dot4f(c[5], wr[5]);
            #pragma unroll
            for (int o = 16; o >= 1; o >>= 1) p += __shfl_xor(p, o, 64);

            const int  rpcur = 2 * pp + half;
            const bool valid = rpcur < Nu;             // diverges only at tail
            if (hl == 0 && valid) s_sc[rid] = p;
            const float s = valid ? p : NEG_INF_;

            // branchless online softmax update (uniform within half-wave)
            const float newm = fmaxf(mw, s);
            const float e  = __expf(s - newm);
            const float sc = __expf(mw - newm);
            lw = lw * sc + e;
            #pragma unroll
            for (int j = 0; j < 6; ++j) {
                acc[j][0] = acc[j][0] * sc + e * c[j][0];
                acc[j][1] = acc[j][1] * sc + e * c[j][1];
                acc[j][2] = acc[j][2] * sc + e * c[j][2];
                acc[j][3] = acc[j][3] * sc + e * c[j][3];
            }
            mw = newm;

            if (havenext) {
                #pragma unroll
                for (int j = 0; j < 6; ++j) c[j] = n[j];
                rid = nrid;
            }
        }
    }

    // ---- store 8 half-wave states ----
    const int hs = (wv_ << 1) | half;
    if (hl == 0) { s_wm[hs] = mw; s_wl[hs] = lw; }
    #pragma unroll
    for (int j = 0; j < 6; ++j)
        *(f4*)&s_acc[hs][hl * 4 + j * 128] = acc[j];
    __syncthreads();

    // ---- merge 8 states ----
    float Mx = MINIT_;
    #pragma unroll
    for (int i = 0; i < 8; ++i) Mx = fmaxf(Mx, s_wm[i]);
    float fm[8], ltot = 0.f;
    #pragma unroll
    for (int i = 0; i < 8; ++i) {
        fm[i] = __expf(s_wm[i] - Mx);
        ltot += s_wl[i] * fm[i];
    }
    const float inv_l = (ltot > 0.f) ? (1.0f / ltot) : 0.f;

    for (int t = tid; t < DT_; t += 256) {
        float v = 0.f;
        #pragma unroll
        for (int i = 0; i < 8; ++i) v += s_acc[i][t] * fm[i];
        s_acc[0][t] = v * inv_l;
    }
    // attn: masked rows have s_sc == -1e30 -> exp underflows to exact 0
    for (int m = tid; m < M_; m += 256)
        out_attn[(size_t)b * M_ + m] = __expf(s_sc[m] - Mx) * inv_l;
    __syncthreads();

    // ---- ctx[d] = sbar . Wv[:,d] ----
    {
        const int d  = lane;
        const int t0 = wv_ * (DT_ / 4);
        float cp = 0.f;
        for (int t = t0; t < t0 + DT_ / 4; ++t)
            cp += s_acc[0][t] * Wv[(size_t)t * DA_ + d];
        s_red[tid] = cp;
    }
    __syncthreads();
    if (tid < DA_)
        s_ctx[tid] = s_red[tid] + s_red[tid + 64] + s_red[tid + 128] + s_red[tid + 192];
    __syncthreads();

    // ---- fused = ctx @ Wo + bo + q_vec ----
    for (int j = tid; j < DQ_; j += 256) {
        float f = bo[j] + s_qv[j];
        #pragma unroll 8
        for (int d = 0; d < DA_; ++d)
            f += s_ctx[d] * Wo[(size_t)d * DQ_ + j];
        out_fused[(size_t)b * DQ_ + j] = f;
    }
}

extern "C" void kernel_launch(void* const* d_in, const int* in_sizes, int n_in,
                              void* d_out, int out_size, void* d_ws, size_t ws_size,
                              hipStream_t stream) {
    (void)in_sizes; (void)n_in; (void)d_ws; (void)ws_size; (void)out_size;

    const float* q_vec = (const float*)d_in[0];
    const float* desc  = (const float*)d_in[1];
    const int*   mask  = (const int*)  d_in[2];
    const float* Wq    = (const float*)d_in[3];
    const float* Wk    = (const float*)d_in[4];
    const float* Wv    = (const float*)d_in[5];
    const float* U     = (const float*)d_in[6];
    const float* Wo    = (const float*)d_in[7];
    const float* bo    = (const float*)d_in[8];

    float* out_fused = (float*)d_out;                     // (B, DQ)
    float* out_attn  = (float*)d_out + (size_t)B_ * DQ_;  // (B, M)

    bilinear_attn_fused<<<dim3(B_), dim3(256), 0, stream>>>(
        q_vec, desc, mask, Wq, Wk, Wv, U, Wo, bo, out_fused, out_attn);
}

// Round 5
// 190.376 us; speedup vs baseline: 1.7330x; 1.0197x over previous
//
#include <hip/hip_runtime.h>
#include <math.h>

#define B_    2048
#define M_    200
#define DQ_   512
#define DT_   768
#define DA_   64
#define G_    4
#define NEG_INF_ (-1e30f)
#define MINIT_  (-3.0e29f)

typedef float f4 __attribute__((ext_vector_type(4)));

__device__ __forceinline__ float dot4f(f4 a, f4 b) {
    return a[0]*b[0] + a[1]*b[1] + a[2]*b[2] + a[3]*b[3];
}

// ---------------- K1: per-batch w vector + compacted row indices ----------
// One block per G_=4 batches. Weights read once per block (4x amortized).
__global__ __launch_bounds__(256)
void prep_kernel(const float* __restrict__ q_vec, const int* __restrict__ mask,
                 const float* __restrict__ Wq, const float* __restrict__ U,
                 const float* __restrict__ Wk,
                 float* __restrict__ w_ws, int* __restrict__ idx_ws,
                 int* __restrict__ cnt_ws)
{
    const int tid  = threadIdx.x;
    const int lane = tid & 63;
    const int wv   = tid >> 6;
    const int b0   = blockIdx.x * G_;

    __shared__ float s_qv[G_][DQ_];   // 8 KB
    __shared__ float s_Q[G_][DA_];
    __shared__ float s_QU[G_][DA_];

    for (int i = tid; i < G_ * DQ_; i += 256)
        ((float*)s_qv)[i] = q_vec[(size_t)b0 * DQ_ + i];
    __syncthreads();

    // Q[g][d] — thread (g = tid>>6, d = tid&63)
    {
        const int g = tid >> 6, d = tid & 63;
        float p = 0.f;
        for (int t = 0; t < DQ_; ++t) p += s_qv[g][t] * Wq[t * DA_ + d];
        s_Q[g][d] = p;
    }
    __syncthreads();
    // QU[g][d]
    {
        const int g = tid >> 6, d = tid & 63;
        float qu = 0.f;
        for (int e = 0; e < DA_; ++e) qu += s_Q[g][e] * U[e * DA_ + d];
        s_QU[g][d] = qu;
    }
    __syncthreads();
    // w[g][t] = Wk[t,:] . QU[g]  (each Wk row read once, 4 batches reuse)
    for (int t = tid; t < DT_; t += 256) {
        const f4* wk4 = (const f4*)(Wk + (size_t)t * DA_);
        float a0 = 0.f, a1 = 0.f, a2 = 0.f, a3 = 0.f;
        #pragma unroll
        for (int i = 0; i < DA_ / 4; ++i) {
            const f4 kk = wk4[i];
            a0 += dot4f(kk, *(const f4*)&s_QU[0][i * 4]);
            a1 += dot4f(kk, *(const f4*)&s_QU[1][i * 4]);
            a2 += dot4f(kk, *(const f4*)&s_QU[2][i * 4]);
            a3 += dot4f(kk, *(const f4*)&s_QU[3][i * 4]);
        }
        w_ws[(size_t)(b0 + 0) * DT_ + t] = a0;
        w_ws[(size_t)(b0 + 1) * DT_ + t] = a1;
        w_ws[(size_t)(b0 + 2) * DT_ + t] = a2;
        w_ws[(size_t)(b0 + 3) * DT_ + t] = a3;
    }
    // ballot-compact unmasked rows: wave wv -> batch b0+wv
    {
        const int b = b0 + wv;
        const int* maskb = mask + (size_t)b * M_;
        int total = 0;
        #pragma unroll
        for (int base = 0; base < 256; base += 64) {
            const int m  = base + lane;
            const int mk = (m < M_) ? maskb[m] : 0;
            const unsigned long long bal = __ballot(mk != 0);
            const int pre = __popcll(bal & ((1ull << lane) - 1ull));
            if (mk) idx_ws[(size_t)b * M_ + total + pre] = m;
            total += __popcll(bal);
        }
        if (lane == 0) cnt_ws[b] = total;
    }
}

// ---------------- K2: lean streaming + softmax + epilogue ------------------
// One block per batch. Target <=64 VGPR -> 8 waves/SIMD (32 waves/CU), 2x R4.
// No software prefetch: occupancy supplies the MLP.
__global__ __launch_bounds__(256, 8)
void stream_kernel(const float* __restrict__ desc,
                   const float* __restrict__ w_ws,
                   const int*   __restrict__ idx_ws,
                   const int*   __restrict__ cnt_ws,
                   const float* __restrict__ q_vec,
                   const float* __restrict__ Wv,
                   const float* __restrict__ Wo,
                   const float* __restrict__ bo,
                   float* __restrict__ out_fused,
                   float* __restrict__ out_attn)
{
    const int b    = blockIdx.x;
    const int tid  = threadIdx.x;
    const int lane = tid & 63;
    const int wv   = tid >> 6;

    __shared__ int   s_idx[M_];
    __shared__ float s_sc[M_];
    __shared__ float s_acc[4][DT_];   // 12 KB
    __shared__ float s_red[256];
    __shared__ float s_wm[4], s_wl[4];
    __shared__ float s_ctx[DA_];

    const int Nu = cnt_ws[b];
    for (int m = tid; m < M_; m += 256) s_sc[m] = NEG_INF_;
    for (int m = tid; m < Nu; m += 256) s_idx[m] = idx_ws[(size_t)b * M_ + m];

    // per-lane w fragments (w row is only 3 KB, L2/HBM tiny)
    const float* wrow = w_ws + (size_t)b * DT_ + lane * 4;
    const f4 w0 = *(const f4*)(wrow);
    const f4 w1 = *(const f4*)(wrow + 256);
    const f4 w2 = *(const f4*)(wrow + 512);
    __syncthreads();

    f4 a0 = {0,0,0,0}, a1 = {0,0,0,0}, a2 = {0,0,0,0};
    float mw = MINIT_, lw = 0.f;

    const float* descb = desc + (size_t)b * (M_ * DT_) + lane * 4;

    for (int j = wv; j < Nu; j += 4) {
        const int rid = s_idx[j];
        const float* r = descb + (size_t)rid * DT_;
        const f4 c0 = *(const f4*)(r);
        const f4 c1 = *(const f4*)(r + 256);
        const f4 c2 = *(const f4*)(r + 512);

        float p = dot4f(c0, w0) + dot4f(c1, w1) + dot4f(c2, w2);
        #pragma unroll
        for (int o = 32; o >= 1; o >>= 1) p += __shfl_xor(p, o, 64);
        if (lane == 0) s_sc[rid] = p;

        // branchless online softmax (p is wave-uniform)
        const float newm = fmaxf(mw, p);
        const float e  = __expf(p - newm);
        const float sc = __expf(mw - newm);
        lw = lw * sc + e;
        a0 = a0 * sc + e * c0;
        a1 = a1 * sc + e * c1;
        a2 = a2 * sc + e * c2;
        mw = newm;
    }

    if (lane == 0) { s_wm[wv] = mw; s_wl[wv] = lw; }
    *(f4*)&s_acc[wv][lane * 4]       = a0;
    *(f4*)&s_acc[wv][lane * 4 + 256] = a1;
    *(f4*)&s_acc[wv][lane * 4 + 512] = a2;
    __syncthreads();

    // merge 4 wave states
    const float m0 = s_wm[0], m1 = s_wm[1], m2 = s_wm[2], m3 = s_wm[3];
    const float Mx = fmaxf(fmaxf(m0, m1), fmaxf(m2, m3));
    const float f0 = __expf(m0 - Mx), f1 = __expf(m1 - Mx);
    const float f2 = __expf(m2 - Mx), f3 = __expf(m3 - Mx);
    const float ltot  = s_wl[0]*f0 + s_wl[1]*f1 + s_wl[2]*f2 + s_wl[3]*f3;
    const float inv_l = (ltot > 0.f) ? (1.0f / ltot) : 0.f;

    for (int t = tid; t < DT_; t += 256)
        s_acc[0][t] = (s_acc[0][t]*f0 + s_acc[1][t]*f1
                     + s_acc[2][t]*f2 + s_acc[3][t]*f3) * inv_l;
    // attn: masked rows keep s_sc == -1e30 -> exp underflows to exact 0
    for (int m = tid; m < M_; m += 256)
        out_attn[(size_t)b * M_ + m] = __expf(s_sc[m] - Mx) * inv_l;
    __syncthreads();

    // ctx[d] = sbar . Wv[:,d]
    {
        const int t0 = wv * (DT_ / 4);
        float cp = 0.f;
        for (int t = t0; t < t0 + DT_ / 4; ++t)
            cp += s_acc[0][t] * Wv[(size_t)t * DA_ + lane];
        s_red[tid] = cp;
    }
    __syncthreads();
    if (tid < DA_)
        s_ctx[tid] = s_red[tid] + s_red[tid + 64] + s_red[tid + 128] + s_red[tid + 192];
    __syncthreads();

    // fused = ctx @ Wo + bo + q_vec
    const float* qrow = q_vec + (size_t)b * DQ_;
    for (int jq = tid; jq < DQ_; jq += 256) {
        float f = bo[jq] + qrow[jq];
        #pragma unroll 8
        for (int d = 0; d < DA_; ++d)
            f += s_ctx[d] * Wo[(size_t)d * DQ_ + jq];
        out_fused[(size_t)b * DQ_ + jq] = f;
    }
}

extern "C" void kernel_launch(void* const* d_in, const int* in_sizes, int n_in,
                              void* d_out, int out_size, void* d_ws, size_t ws_size,
                              hipStream_t stream) {
    (void)in_sizes; (void)n_in; (void)ws_size; (void)out_size;

    const float* q_vec = (const float*)d_in[0];
    const float* desc  = (const float*)d_in[1];
    const int*   mask  = (const int*)  d_in[2];
    const float* Wq    = (const float*)d_in[3];
    const float* Wk    = (const float*)d_in[4];
    const float* Wv    = (const float*)d_in[5];
    const float* U     = (const float*)d_in[6];
    const float* Wo    = (const float*)d_in[7];
    const float* bo    = (const float*)d_in[8];

    float* out_fused = (float*)d_out;                     // (B, DQ)
    float* out_attn  = (float*)d_out + (size_t)B_ * DQ_;  // (B, M)

    // workspace layout
    float* w_ws   = (float*)d_ws;                         // B*DT floats (6.29 MB)
    int*   idx_ws = (int*)((char*)d_ws + (size_t)B_ * DT_ * sizeof(float)); // B*M ints
    int*   cnt_ws = idx_ws + (size_t)B_ * M_;             // B ints

    prep_kernel<<<dim3(B_ / G_), dim3(256), 0, stream>>>(
        q_vec, mask, Wq, U, Wk, w_ws, idx_ws, cnt_ws);

    stream_kernel<<<dim3(B_), dim3(256), 0, stream>>>(
        desc, w_ws, idx_ws, cnt_ws, q_vec, Wv, Wo, bo, out_fused, out_attn);
}